// Round 15
// baseline (344.106 us; speedup 1.0000x reference)
//
#include <hip/hip_runtime.h>
#include <math.h>

// ============================================================================
// R27: R26 base (317.6us) + scores_k Q-reuse pairing.
// scores_k (71.6us, all of top-5): 8/10 staging gloads per K-iter are the Q
// tile, re-staged for every s-tile sharing it (the R20/R26 replication
// pattern). Fix: each block does TWO s-tiles per Q staging: LDS Q(32K)+
// K0+K1(16K)=48KB; 12 gloads + 96 MFMA/wave per iter (staging -40%,
// barriers/MFMA halved). acc doubles (~190 VGPR < 256, no spill expected).
// Pair enumeration XCD-balanced: complementary (tt,31-tt) rows = exactly 17
// pairs, so group g=gx&7 holds {g,31-g,g+8,23-g}=34 blocks and gx=g+8j pins
// each Q-tile's sp-range to ONE XCD (keeps R18 locality win) with equal
// work/XCD. Grid (272,2); lone odd tile via block-uniform hasB. MFMA order
// per tile unchanged -> bit-identical numerics (absmax 0.015625 expected).
// Predicted: scores 71.6->~50-58us, FETCH 53->~35MB, total ~295-305us.
// ============================================================================

#define B_ 2
#define T_ 2048
#define C_ 512
#define NB_ 4
#define C2_ 1024  // hi|lo row width

typedef unsigned short u16;
typedef unsigned char u8;
using short8 = __attribute__((ext_vector_type(8))) short;
using bf16x8 = __attribute__((ext_vector_type(8))) __bf16;
using f32x4  = __attribute__((ext_vector_type(4))) float;

__device__ __forceinline__ float bf2f(u16 u) {
  union { unsigned int i; float f; } v; v.i = ((unsigned int)u) << 16; return v.f;
}
__device__ __forceinline__ u16 f2bf(float f) {  // round-to-nearest-even
  union { float f; unsigned int i; } v; v.f = f;
  unsigned int u = v.i;
  return (u16)((u + 0x7fffu + ((u >> 16) & 1u)) >> 16);
}
__device__ __forceinline__ f32x4 mfma16x16x32(short8 a, short8 b, f32x4 c) {
  return __builtin_amdgcn_mfma_f32_16x16x32_bf16(
      __builtin_bit_cast(bf16x8, a), __builtin_bit_cast(bf16x8, b), c, 0, 0, 0);
}
__device__ __forceinline__ void split8(const float* s, uint4& hi, uint4& lo) {
  u16 h[8], l[8];
#pragma unroll
  for (int j = 0; j < 8; ++j) {
    h[j] = f2bf(s[j]);
    l[j] = f2bf(s[j] - bf2f(h[j]));
  }
  hi.x = h[0] | ((unsigned)h[1] << 16); hi.y = h[2] | ((unsigned)h[3] << 16);
  hi.z = h[4] | ((unsigned)h[5] << 16); hi.w = h[6] | ((unsigned)h[7] << 16);
  lo.x = l[0] | ((unsigned)l[1] << 16); lo.y = l[2] | ((unsigned)l[3] << 16);
  lo.z = l[4] | ((unsigned)l[5] << 16); lo.w = l[6] | ((unsigned)l[7] << 16);
}
// LDS bank swizzle: XOR the 16B column-group with row bits [2:1].
__device__ __forceinline__ int swz(int row) { return ((row >> 1) & 3) << 3; }

// ---------------------------------------------------------------------------
// Pre-pass 1: a (4096x512 f32) -> Acat (4096 x [hi512|lo512] u16).
// ---------------------------------------------------------------------------
__global__ __launch_bounds__(256) void split_a_k(const float* __restrict__ A,
                                                 u16* __restrict__ Acat) {
  const size_t base = ((size_t)blockIdx.x * 256 + threadIdx.x) << 3;
  const size_t row = base >> 9, col = base & 511;
  float av[8];
  *(float4*)(av) = *(const float4*)(&A[base]);
  *(float4*)(av + 4) = *(const float4*)(&A[base + 4]);
  uint4 hi, lo;
  split8(av, hi, lo);
  *(uint4*)(&Acat[row * C2_ + col]) = hi;
  *(uint4*)(&Acat[row * C2_ + C_ + col]) = lo;
}

// ---------------------------------------------------------------------------
// Pre-pass 2: W (512 x N f32) -> WT (N x [hi|lo] or hi-only), transposed.
// ---------------------------------------------------------------------------
template <int HILO>
__global__ __launch_bounds__(256) void splitT_w_k(const float* __restrict__ W,
                                                  u16* __restrict__ WT,
                                                  const int N) {
  __shared__ float tile[64][68];
  const int n0 = blockIdx.x << 6, k0 = blockIdx.y << 6;
  const int tid = threadIdx.x;
  const int rr = tid >> 4, cc = (tid & 15) << 2;
#pragma unroll
  for (int it = 0; it < 4; ++it) {
    const int kr = (it << 4) + rr;
    *(float4*)(&tile[kr][cc]) =
        *(const float4*)(&W[(size_t)(k0 + kr) * N + n0 + cc]);
  }
  __syncthreads();
  const int W2 = HILO ? C2_ : C_;
#pragma unroll
  for (int it = 0; it < 4; ++it) {
    const int nr = (it << 4) + rr;
    const int kc = cc;
    float v[4] = {tile[kc][nr], tile[kc + 1][nr], tile[kc + 2][nr],
                  tile[kc + 3][nr]};
    ushort4 hw, lw;
    hw.x = f2bf(v[0]); hw.y = f2bf(v[1]); hw.z = f2bf(v[2]); hw.w = f2bf(v[3]);
    *(ushort4*)(&WT[(size_t)(n0 + nr) * W2 + k0 + kc]) = hw;
    if (HILO) {
      lw.x = f2bf(v[0] - bf2f(hw.x)); lw.y = f2bf(v[1] - bf2f(hw.y));
      lw.z = f2bf(v[2] - bf2f(hw.z)); lw.w = f2bf(v[3] - bf2f(hw.w));
      *(ushort4*)(&WT[(size_t)(n0 + nr) * W2 + C_ + k0 + kc]) = lw;
    }
  }
}

// ---------------------------------------------------------------------------
// Q GEMM from pre-split inputs: Acat @ WTq -> Qcat with fused RoPE + scale.
// ---------------------------------------------------------------------------
__global__ __launch_bounds__(256) void gemm_qk_pre(const u16* __restrict__ Acat,
                                                   const u16* __restrict__ WT,
                                                   u16* __restrict__ out,
                                                   const float* __restrict__ cosT,
                                                   const float* __restrict__ sinT) {
  __shared__ __align__(16) u16 Ah[64][32], Al[64][32];
  __shared__ __align__(16) u16 Bh[64][32], Bl[64][32];
  const int tid = threadIdx.x;
  const int wave = tid >> 6, lane = tid & 63;
  const int m0 = blockIdx.y << 6, n0 = blockIdx.x << 6;
  const f32x4 zero = {0.f, 0.f, 0.f, 0.f};
  f32x4 acc[4] = {zero, zero, zero, zero};
  const int srow = tid >> 2, kg = (tid & 3) << 3;
  const int lrow = lane & 15, lk = (lane >> 4) << 3;
  const int wrow = wave << 4;
  const size_t abase = (size_t)(m0 + srow) * C2_ + kg;
  const size_t bbase = (size_t)(n0 + srow) * C2_ + kg;
  for (int kk = 0; kk < C_; kk += 32) {
    __builtin_amdgcn_global_load_lds(
        (const __attribute__((address_space(1))) void*)&Acat[abase + kk],
        (__attribute__((address_space(3))) void*)&Ah[wrow][0], 16, 0, 0);
    __builtin_amdgcn_global_load_lds(
        (const __attribute__((address_space(1))) void*)&Acat[abase + C_ + kk],
        (__attribute__((address_space(3))) void*)&Al[wrow][0], 16, 0, 0);
    __builtin_amdgcn_global_load_lds(
        (const __attribute__((address_space(1))) void*)&WT[bbase + kk],
        (__attribute__((address_space(3))) void*)&Bh[wrow][0], 16, 0, 0);
    __builtin_amdgcn_global_load_lds(
        (const __attribute__((address_space(1))) void*)&WT[bbase + C_ + kk],
        (__attribute__((address_space(3))) void*)&Bl[wrow][0], 16, 0, 0);
    __syncthreads();
    short8 ah = *(const short8*)(&Ah[(wave << 4) + lrow][lk]);
    short8 al = *(const short8*)(&Al[(wave << 4) + lrow][lk]);
#pragma unroll
    for (int ns = 0; ns < 4; ++ns) {
      short8 bh = *(const short8*)(&Bh[(ns << 4) + lrow][lk]);
      short8 bl = *(const short8*)(&Bl[(ns << 4) + lrow][lk]);
      acc[ns] = mfma16x16x32(ah, bh, acc[ns]);
      acc[ns] = mfma16x16x32(al, bh, acc[ns]);
      acc[ns] = mfma16x16x32(ah, bl, acc[ns]);
    }
    __syncthreads();
  }
  const int r0 = m0 + (wave << 4) + ((lane >> 4) << 2);
  const int cb = n0 + (lane & 15);
#pragma unroll
  for (int ns = 0; ns < 4; ++ns) {
#pragma unroll
    for (int r = 0; r < 4; ++r) {
      const int rg = r0 + r;
      const int cg = cb + (ns << 4);
      float v = acc[ns][r];
      float pv = __shfl_xor(v, 1);  // partner column of the RoPE pair
      const int t = rg & (T_ - 1);
      const int c = cg & (C_ - 1);
      const int i = c >> 1;
      const float cf = cosT[(t << 8) + i];
      const float sf = sinT[(t << 8) + i];
      float x1 = (lane & 1) ? pv : v;
      float x2 = (lane & 1) ? v : pv;
      float y = (lane & 1) ? (x1 * sf + x2 * cf) : (x1 * cf - x2 * sf);
      y *= 0.044194173824159216f;  // 1/sqrt(512)
      const u16 hi = f2bf(y);
      const u16 lo = f2bf(y - bf2f(hi));
      const int b = rg >> 11, n = cg >> 9;
      const size_t rowoff = ((size_t)((b * NB_ + n) * T_ + t)) * C2_;
      out[rowoff + c] = hi;
      out[rowoff + C_ + c] = lo;
    }
  }
}

// ---------------------------------------------------------------------------
// a@Wv from pre-split inputs: Acat hi-half @ WTv -> Vraw bf16 (4096x2048).
// ---------------------------------------------------------------------------
__global__ __launch_bounds__(256) void gemm_bb(const u16* __restrict__ Acat,
                                               const u16* __restrict__ WT,
                                               u16* __restrict__ out) {
  __shared__ __align__(16) u16 As[64][32];
  __shared__ __align__(16) u16 Bs[64][32];
  const int tid = threadIdx.x;
  const int wave = tid >> 6, lane = tid & 63;
  const int m0 = blockIdx.y << 6, n0 = blockIdx.x << 6;
  const f32x4 zero = {0.f, 0.f, 0.f, 0.f};
  f32x4 acc[4] = {zero, zero, zero, zero};
  const int srow = tid >> 2, kg = (tid & 3) << 3;
  const int lrow = lane & 15, lk = (lane >> 4) << 3;
  const int wrow = wave << 4;
  const size_t abase = (size_t)(m0 + srow) * C2_ + kg;  // hi half of Acat
  const size_t bbase = (size_t)(n0 + srow) * C_ + kg;   // WTv row width 512
  for (int kk = 0; kk < C_; kk += 32) {
    __builtin_amdgcn_global_load_lds(
        (const __attribute__((address_space(1))) void*)&Acat[abase + kk],
        (__attribute__((address_space(3))) void*)&As[wrow][0], 16, 0, 0);
    __builtin_amdgcn_global_load_lds(
        (const __attribute__((address_space(1))) void*)&WT[bbase + kk],
        (__attribute__((address_space(3))) void*)&Bs[wrow][0], 16, 0, 0);
    __syncthreads();
    short8 af = *(const short8*)(&As[(wave << 4) + lrow][lk]);
#pragma unroll
    for (int ns = 0; ns < 4; ++ns) {
      short8 bf = *(const short8*)(&Bs[(ns << 4) + lrow][lk]);
      acc[ns] = mfma16x16x32(af, bf, acc[ns]);
    }
    __syncthreads();
  }
  const int r0 = m0 + (wave << 4) + ((lane >> 4) << 2);
  const int cb = n0 + (lane & 15);
#pragma unroll
  for (int ns = 0; ns < 4; ++ns) {
#pragma unroll
    for (int r = 0; r < 4; ++r) {
      out[(size_t)(r0 + r) * (NB_ * C_) + cb + (ns << 4)] = f2bf(acc[ns][r]);
    }
  }
}

// ---------------------------------------------------------------------------
// Split-precision GEMM with fused RoPE (kept for x @ Wk -> Kcat only).
// ---------------------------------------------------------------------------
template <int MODE>
__global__ __launch_bounds__(256) void gemm_qk(const float* __restrict__ A,
                                               const float* __restrict__ W,
                                               u16* __restrict__ out,
                                               const float* __restrict__ cosT,
                                               const float* __restrict__ sinT,
                                               const int N, const int K) {
  __shared__ u16 Ah[64][32], Al[64][32];
  __shared__ u16 Bh[64][32], Bl[64][32];  // [n][k]
  const int tid = threadIdx.x;
  const int wave = tid >> 6, lane = tid & 63;
  const int m0 = blockIdx.y << 6, n0 = blockIdx.x << 6;
  const f32x4 zero = {0.f, 0.f, 0.f, 0.f};
  f32x4 acc[4] = {zero, zero, zero, zero};
  const int srow = tid >> 2, koff = ((tid & 3) << 3) ^ swz(tid >> 2);
  const int lrow = lane & 15, lk = ((lane >> 4) << 3) ^ swz(lane & 15);
  for (int kk = 0; kk < K; kk += 32) {
    const int kg = (tid & 3) << 3;  // global k sub-offset (unswizzled)
    float av[8];
    *(float4*)(av) = *(const float4*)(&A[(size_t)(m0 + srow) * K + kk + kg]);
    *(float4*)(av + 4) =
        *(const float4*)(&A[(size_t)(m0 + srow) * K + kk + kg + 4]);
    uint4 hi, lo;
    split8(av, hi, lo);
    *(uint4*)(&Ah[srow][koff]) = hi;
    *(uint4*)(&Al[srow][koff]) = lo;
    float wv[8];
#pragma unroll
    for (int j = 0; j < 8; ++j)
      wv[j] = W[(size_t)(kk + kg + j) * N + n0 + srow];
    split8(wv, hi, lo);
    *(uint4*)(&Bh[srow][koff]) = hi;
    *(uint4*)(&Bl[srow][koff]) = lo;
    __syncthreads();
    short8 ah = *(const short8*)(&Ah[(wave << 4) + lrow][lk]);
    short8 al = *(const short8*)(&Al[(wave << 4) + lrow][lk]);
#pragma unroll
    for (int ns = 0; ns < 4; ++ns) {
      short8 bh = *(const short8*)(&Bh[(ns << 4) + lrow][lk]);
      short8 bl = *(const short8*)(&Bl[(ns << 4) + lrow][lk]);
      acc[ns] = mfma16x16x32(ah, bh, acc[ns]);
      acc[ns] = mfma16x16x32(al, bh, acc[ns]);
      acc[ns] = mfma16x16x32(ah, bl, acc[ns]);
    }
    __syncthreads();
  }
  const int r0 = m0 + (wave << 4) + ((lane >> 4) << 2);
  const int cb = n0 + (lane & 15);
#pragma unroll
  for (int ns = 0; ns < 4; ++ns) {
#pragma unroll
    for (int r = 0; r < 4; ++r) {
      const int rg = r0 + r;
      const int cg = cb + (ns << 4);
      float v = acc[ns][r];
      float pv = __shfl_xor(v, 1);  // partner column of the RoPE pair
      const int t = rg & (T_ - 1);
      const int c = (MODE == 1) ? (cg & (C_ - 1)) : cg;
      const int i = c >> 1;
      const float cf = cosT[(t << 8) + i];
      const float sf = sinT[(t << 8) + i];
      float x1 = (lane & 1) ? pv : v;
      float x2 = (lane & 1) ? v : pv;
      float y = (lane & 1) ? (x1 * sf + x2 * cf) : (x1 * cf - x2 * sf);
      if (MODE == 1) y *= 0.044194173824159216f;  // 1/sqrt(512)
      const u16 hi = f2bf(y);
      const u16 lo = f2bf(y - bf2f(hi));
      size_t rowoff;
      if (MODE == 1) {
        const int b = rg >> 11, n = cg >> 9;
        rowoff = ((size_t)((b * NB_ + n) * T_ + t)) * C2_;
      } else {
        rowoff = (size_t)rg * C2_;
      }
      out[rowoff + c] = hi;
      out[rowoff + C_ + c] = lo;
    }
  }
}

// ---------------------------------------------------------------------------
// Plain hi-only GEMM (kept for Y @ Wo): A bf16, W f32; out f32.
// ---------------------------------------------------------------------------
template <int AF32, int OF32>
__global__ __launch_bounds__(256) void gemm_hi(const void* __restrict__ Ap,
                                               const float* __restrict__ W,
                                               void* __restrict__ outp,
                                               const int N, const int K) {
  __shared__ u16 As[64][32];
  __shared__ u16 Bs[64][32];
  const int tid = threadIdx.x;
  const int wave = tid >> 6, lane = tid & 63;
  const int m0 = blockIdx.y << 6, n0 = blockIdx.x << 6;
  const f32x4 zero = {0.f, 0.f, 0.f, 0.f};
  f32x4 acc[4] = {zero, zero, zero, zero};
  const int srow = tid >> 2, koff = ((tid & 3) << 3) ^ swz(tid >> 2);
  const int lrow = lane & 15, lk = ((lane >> 4) << 3) ^ swz(lane & 15);
  for (int kk = 0; kk < K; kk += 32) {
    const int kg = (tid & 3) << 3;
    if (AF32) {
      const float* A = (const float*)Ap;
      float av[8];
      *(float4*)(av) = *(const float4*)(&A[(size_t)(m0 + srow) * K + kk + kg]);
      *(float4*)(av + 4) =
          *(const float4*)(&A[(size_t)(m0 + srow) * K + kk + kg + 4]);
      uint4 hi;
      hi.x = f2bf(av[0]) | ((unsigned)f2bf(av[1]) << 16);
      hi.y = f2bf(av[2]) | ((unsigned)f2bf(av[3]) << 16);
      hi.z = f2bf(av[4]) | ((unsigned)f2bf(av[5]) << 16);
      hi.w = f2bf(av[6]) | ((unsigned)f2bf(av[7]) << 16);
      *(uint4*)(&As[srow][koff]) = hi;
    } else {
      const u16* A = (const u16*)Ap;
      *(uint4*)(&As[srow][koff]) =
          *(const uint4*)(&A[(size_t)(m0 + srow) * K + kk + kg]);
    }
    uint4 hi;
    {
      float w[8];
#pragma unroll
      for (int j = 0; j < 8; ++j)
        w[j] = W[(size_t)(kk + kg + j) * N + n0 + srow];
      hi.x = f2bf(w[0]) | ((unsigned)f2bf(w[1]) << 16);
      hi.y = f2bf(w[2]) | ((unsigned)f2bf(w[3]) << 16);
      hi.z = f2bf(w[4]) | ((unsigned)f2bf(w[5]) << 16);
      hi.w = f2bf(w[6]) | ((unsigned)f2bf(w[7]) << 16);
    }
    *(uint4*)(&Bs[srow][koff]) = hi;
    __syncthreads();
    short8 af = *(const short8*)(&As[(wave << 4) + lrow][lk]);
#pragma unroll
    for (int ns = 0; ns < 4; ++ns) {
      short8 bf = *(const short8*)(&Bs[(ns << 4) + lrow][lk]);
      acc[ns] = mfma16x16x32(af, bf, acc[ns]);
    }
    __syncthreads();
  }
  const int r0 = m0 + (wave << 4) + ((lane >> 4) << 2);
  const int cb = n0 + (lane & 15);
#pragma unroll
  for (int ns = 0; ns < 4; ++ns) {
#pragma unroll
    for (int r = 0; r < 4; ++r) {
      const size_t idx = (size_t)(r0 + r) * N + cb + (ns << 4);
      if (OF32) ((float*)outp)[idx] = acc[ns][r];
      else ((u16*)outp)[idx] = f2bf(acc[ns][r]);
    }
  }
}

// ---------------------------------------------------------------------------
// Vraw (B,T,NB*C) bf16 -> VT (B,NB,C,T) tiled transpose, 64x64 tiles.
// ---------------------------------------------------------------------------
__global__ __launch_bounds__(256) void transpose_v_k(const u16* __restrict__ Vraw,
                                                     u16* __restrict__ VT) {
  const int bid = blockIdx.x;
  const int ct = bid & 7;
  const int ttile = (bid >> 3) & 31;
  const int n = (bid >> 8) & 3;
  const int b = bid >> 10;
  __shared__ u16 tile[64][68];
  const int tid = threadIdx.x;
  const int rr = tid >> 4;
  const int cc = (tid & 15) << 2;
  const int t0 = ttile << 6, c0 = ct << 6;
#pragma unroll
  for (int it = 0; it < 4; ++it) {
    const int r = (it << 4) + rr;
    *(ushort4*)(&tile[r][cc]) = *(const ushort4*)(
        &Vraw[((size_t)((b << 11) + t0 + r)) * (NB_ * C_) + n * C_ + c0 + cc]);
  }
  __syncthreads();
#pragma unroll
  for (int it = 0; it < 4; ++it) {
    const int c = (it << 4) + rr;
    ushort4 w;
    w.x = tile[cc + 0][c]; w.y = tile[cc + 1][c];
    w.z = tile[cc + 2][c]; w.w = tile[cc + 3][c];
    *(ushort4*)(&VT[((size_t)((b * NB_ + n) * C_ + c0 + c)) * T_ + t0 + cc]) = w;
  }
}

// ---------------------------------------------------------------------------
// Scores (R27): paired s-tiles per Q staging. Block handles s-tiles
// {2sp, 2sp+1 (if <=tt)} of row tt. LDS: Q 32KB + K0/K1 16KB = 48KB.
// Per K-iter: 12 gload_lds + 96 MFMA/wave. XCD-balanced decode: group
// g=gx&7 covers tt in {g,31-g,g+8,23-g} (= exactly 34 pair-blocks); gx=g+8j
// => id%8==g pins each Q-tile's sp-range to one XCD. Grid (272, 2).
// ---------------------------------------------------------------------------
__global__ __launch_bounds__(256) void scores_k(const u16* __restrict__ Qcat,
                                                const u16* __restrict__ Kcat,
                                                u16* __restrict__ Mout,
                                                u8* __restrict__ Mask) {
  const int gx = blockIdx.x;          // 0..271
  const int g = gx & 7, j = gx >> 3;  // XCD group, index within group (0..33)
  const int b = blockIdx.y;
  const int ttA = g, ttB = 31 - g, ttC = g + 8;
  const int pA = (ttA >> 1) + 1, pB = (ttB >> 1) + 1, pC = (ttC >> 1) + 1;
  int tt, sp;
  if (j < pA)           { tt = ttA; sp = j; }
  else if (j < pA + pB) { tt = ttB; sp = j - pA; }
  else if (j < pA + pB + pC) { tt = ttC; sp = j - pA - pB; }
  else                  { tt = 23 - g; sp = j - pA - pB - pC; }
  const int t0 = tt << 6;
  const int s0a = (sp << 1) << 6;
  const bool hasB = ((sp << 1) + 1) <= tt;
  const int s0b = s0a + 64;

  __shared__ __align__(16) u16 Qh[NB_][64][32], Ql[NB_][64][32];
  __shared__ __align__(16) u16 K0h[64][32], K0l[64][32];
  __shared__ __align__(16) u16 K1h[64][32], K1l[64][32];
  const int tid = threadIdx.x;
  const int wave = tid >> 6, lane = tid & 63;
  const f32x4 zero = {0.f, 0.f, 0.f, 0.f};
  f32x4 accA[NB_][4], accB[NB_][4];
  for (int n = 0; n < NB_; ++n)
    for (int q = 0; q < 4; ++q) { accA[n][q] = zero; accB[n][q] = zero; }
  const int srow = tid >> 2, kg = (tid & 3) << 3;
  const int lrow = lane & 15, lk = (lane >> 4) << 3;
  const int wrow = wave << 4;
  const size_t qstride = (size_t)T_ * C2_;
  const size_t qbase = ((size_t)(b * NB_ * T_ + t0 + srow)) * C2_ + kg;
  const size_t k0base = ((size_t)((b << 11) + s0a + srow)) * C2_ + kg;
  const size_t k1base = ((size_t)((b << 11) + s0b + srow)) * C2_ + kg;

  for (int kk = 0; kk < C_; kk += 32) {
#pragma unroll
    for (int n = 0; n < NB_; ++n) {
      const size_t qb = qbase + (size_t)n * qstride + kk;
      __builtin_amdgcn_global_load_lds(
          (const __attribute__((address_space(1))) void*)&Qcat[qb],
          (__attribute__((address_space(3))) void*)&Qh[n][wrow][0], 16, 0, 0);
      __builtin_amdgcn_global_load_lds(
          (const __attribute__((address_space(1))) void*)&Qcat[qb + C_],
          (__attribute__((address_space(3))) void*)&Ql[n][wrow][0], 16, 0, 0);
    }
    __builtin_amdgcn_global_load_lds(
        (const __attribute__((address_space(1))) void*)&Kcat[k0base + kk],
        (__attribute__((address_space(3))) void*)&K0h[wrow][0], 16, 0, 0);
    __builtin_amdgcn_global_load_lds(
        (const __attribute__((address_space(1))) void*)&Kcat[k0base + kk + C_],
        (__attribute__((address_space(3))) void*)&K0l[wrow][0], 16, 0, 0);
    if (hasB) {
      __builtin_amdgcn_global_load_lds(
          (const __attribute__((address_space(1))) void*)&Kcat[k1base + kk],
          (__attribute__((address_space(3))) void*)&K1h[wrow][0], 16, 0, 0);
      __builtin_amdgcn_global_load_lds(
          (const __attribute__((address_space(1))) void*)&Kcat[k1base + kk + C_],
          (__attribute__((address_space(3))) void*)&K1l[wrow][0], 16, 0, 0);
    }
    __syncthreads();  // drains vmcnt(0): staged data visible block-wide
    short8 qh[NB_], ql[NB_];
#pragma unroll
    for (int n = 0; n < NB_; ++n) {
      qh[n] = *(const short8*)(&Qh[n][wrow + lrow][lk]);
      ql[n] = *(const short8*)(&Ql[n][wrow + lrow][lk]);
    }
#pragma unroll
    for (int ns = 0; ns < 4; ++ns) {
      short8 kh = *(const short8*)(&K0h[(ns << 4) + lrow][lk]);
      short8 kl = *(const short8*)(&K0l[(ns << 4) + lrow][lk]);
#pragma unroll
      for (int n = 0; n < NB_; ++n) {
        accA[n][ns] = mfma16x16x32(qh[n], kh, accA[n][ns]);
        accA[n][ns] = mfma16x16x32(ql[n], kh, accA[n][ns]);
        accA[n][ns] = mfma16x16x32(qh[n], kl, accA[n][ns]);
      }
    }
    if (hasB) {
#pragma unroll
      for (int ns = 0; ns < 4; ++ns) {
        short8 kh = *(const short8*)(&K1h[(ns << 4) + lrow][lk]);
        short8 kl = *(const short8*)(&K1l[(ns << 4) + lrow][lk]);
#pragma unroll
        for (int n = 0; n < NB_; ++n) {
          accB[n][ns] = mfma16x16x32(qh[n], kh, accB[n][ns]);
          accB[n][ns] = mfma16x16x32(ql[n], kh, accB[n][ns]);
          accB[n][ns] = mfma16x16x32(qh[n], kl, accB[n][ns]);
        }
      }
    }
    __syncthreads();  // all reads done before next-iter re-stage
  }
  const int tb = t0 + (wave << 4) + ((lane >> 4) << 2);
#pragma unroll
  for (int ns = 0; ns < 4; ++ns) {
#pragma unroll
    for (int r = 0; r < 4; ++r) {
      const int t = tb + r;
      {  // tile A
        const int s = s0a + (lane & 15) + (ns << 4);
        float a0 = accA[0][ns][r], a1 = accA[1][ns][r];
        float a2 = accA[2][ns][r], a3 = accA[3][ns][r];
        float m = fmaxf(fmaxf(a0, a1), fmaxf(a2, a3));
        u8 msk = (u8)((a0 == m) | ((a1 == m) << 1) | ((a2 == m) << 2) |
                      ((a3 == m) << 3));
        if (s > t) { m = -__builtin_inff(); msk = 0; }
        const size_t idx = (size_t)b * T_ * T_ + (size_t)t * T_ + s;
        Mout[idx] = f2bf(m);
        Mask[idx] = msk;
      }
      if (hasB) {  // tile B
        const int s = s0b + (lane & 15) + (ns << 4);
        float a0 = accB[0][ns][r], a1 = accB[1][ns][r];
        float a2 = accB[2][ns][r], a3 = accB[3][ns][r];
        float m = fmaxf(fmaxf(a0, a1), fmaxf(a2, a3));
        u8 msk = (u8)((a0 == m) | ((a1 == m) << 1) | ((a2 == m) << 2) |
                      ((a3 == m) << 3));
        if (s > t) { m = -__builtin_inff(); msk = 0; }
        const size_t idx = (size_t)b * T_ * T_ + (size_t)t * T_ + s;
        Mout[idx] = f2bf(m);
        Mask[idx] = msk;
      }
    }
  }
}

// ---------------------------------------------------------------------------
// Per-row softmax stats from bf16 M: rowmax, 1/sum(exp). One wave per (b,t).
// ---------------------------------------------------------------------------
__global__ __launch_bounds__(256) void rowstats_k(const u16* __restrict__ Mb,
                                                  float* __restrict__ Rm,
                                                  float* __restrict__ Rz) {
  const int r = (blockIdx.x << 2) + (threadIdx.x >> 6);
  const int lane = threadIdx.x & 63;
  const int b = r >> 11, t = r & (T_ - 1);
  const u16* row = Mb + (size_t)b * T_ * T_ + (size_t)t * T_;
  float m = -__builtin_inff();
  for (int s = lane; s <= t; s += 64) m = fmaxf(m, bf2f(row[s]));
#pragma unroll
  for (int off = 32; off; off >>= 1) m = fmaxf(m, __shfl_xor(m, off));
  float z = 0.f;
  for (int s = lane; s <= t; s += 64) z += __expf(bf2f(row[s]) - m);
#pragma unroll
  for (int off = 32; off; off >>= 1) z += __shfl_xor(z, off);
  if (lane == 0) { Rm[r] = m; Rz[r] = 1.f / z; }
}

// ---------------------------------------------------------------------------
// Routed PV (R25 form, unchanged): depth-2 named A/B register prefetch,
// 512-thread blocks, 64-wide c stripe, grid (8,16,2) XCD V-panel pinning,
// fused P-build + __expf, LDS 32KB, col^swz(row) LDS swizzle.
// ---------------------------------------------------------------------------
__global__ __launch_bounds__(512) void pv_k(const u16* __restrict__ Mb,
                                            const float* __restrict__ Rm,
                                            const float* __restrict__ Rz,
                                            const u8* __restrict__ Mask,
                                            const u16* __restrict__ VT,
                                            u16* __restrict__ Y) {
  const int cblk = blockIdx.x, ypair = blockIdx.y, b = blockIdx.z;
  const int c0 = cblk << 6;  // 64-wide c stripe
  __shared__ u16 Ps[NB_][64][32];
  __shared__ u16 Vs[NB_][64][32];
  const int tid = threadIdx.x;
  const int wave = tid >> 6, lane = tid & 63;
  const int wq = wave & 3, ch = wave >> 2;            // t-quarter, c-half
  const int row8 = tid >> 3, off4 = (tid & 7) << 2;   // 64 rows x uint2
  const int scol = off4 ^ swz(row8);                  // swizzled LDS col
  const int lrow = lane & 15, lk = ((lane >> 4) << 3) ^ swz(lane & 15);
  const f32x4 zero = {0.f, 0.f, 0.f, 0.f};
  const size_t vrow_base[NB_] = {
      ((size_t)((b * NB_ + 0) * C_ + c0 + row8)) * T_,
      ((size_t)((b * NB_ + 1) * C_ + c0 + row8)) * T_,
      ((size_t)((b * NB_ + 2) * C_ + c0 + row8)) * T_,
      ((size_t)((b * NB_ + 3) * C_ + c0 + row8)) * T_};

  for (int half = 0; half < 2; ++half) {
    const int tt = half ? (31 - ypair) : ypair;
    const int t0 = tt << 6;
    const int nchunk = (tt + 1) << 1;  // ALWAYS EVEN
    const int rg = (b << 11) + t0 + row8;       // this thread's (b,t) row
    const size_t pro = (size_t)rg << 11;
    const float rm = Rm[rg], rz = Rz[rg];       // per-row scalars, once/half
    f32x4 acc[2] = {zero, zero};
    // Named depth-2 prefetch sets (rule #20: no runtime-indexed reg arrays).
    uint2 puA, puB; unsigned mkA, mkB; uint2 vvA[NB_], vvB[NB_];

    // prologue: chunk 0 -> A, chunk 1 -> B
    puA = *(const uint2*)(&Mb[pro + off4]);
    mkA = *(const unsigned*)(&Mask[pro + off4]);
#pragma unroll
    for (int n = 0; n < NB_; ++n)
      vvA[n] = *(const uint2*)(&VT[vrow_base[n] + off4]);
    puB = *(const uint2*)(&Mb[pro + 32 + off4]);
    mkB = *(const unsigned*)(&Mask[pro + 32 + off4]);
#pragma unroll
    for (int n = 0; n < NB_; ++n)
      vvB[n] = *(const uint2*)(&VT[vrow_base[n] + 32 + off4]);

    for (int ck = 0; ck < nchunk; ck += 2) {
      // ---- even chunk: consume A; re-issue A <- ck+2 ----
      {
        u16 m4[4] = {(u16)puA.x, (u16)(puA.x >> 16), (u16)puA.y,
                     (u16)(puA.y >> 16)};
        u16 p[4];
#pragma unroll
        for (int j = 0; j < 4; ++j)
          p[j] = f2bf(__expf(bf2f(m4[j]) - rm) * rz);
        u8 mk[4] = {(u8)mkA, (u8)(mkA >> 8), (u8)(mkA >> 16), (u8)(mkA >> 24)};
#pragma unroll
        for (int n = 0; n < NB_; ++n) {
          uint2 wv;
          wv.x = (unsigned)(((mk[0] >> n) & 1) ? p[0] : 0) |
                 ((unsigned)(((mk[1] >> n) & 1) ? p[1] : 0) << 16);
          wv.y = (unsigned)(((mk[2] >> n) & 1) ? p[2] : 0) |
                 ((unsigned)(((mk[3] >> n) & 1) ? p[3] : 0) << 16);
          *(uint2*)(&Ps[n][row8][scol]) = wv;
          *(uint2*)(&Vs[n][row8][scol]) = vvA[n];
        }
        if (ck + 2 < nchunk) {  // A regs free -> issue ck+2 (2-chunk coverage)
          const int sB = (ck + 2) << 5;
          puA = *(const uint2*)(&Mb[pro + sB + off4]);
          mkA = *(const unsigned*)(&Mask[pro + sB + off4]);
#pragma unroll
          for (int n = 0; n < NB_; ++n)
            vvA[n] = *(const uint2*)(&VT[vrow_base[n] + sB + off4]);
        }
        __syncthreads();
#pragma unroll
        for (int n = 0; n < NB_; ++n) {
          short8 af = *(const short8*)(&Ps[n][(wq << 4) + lrow][lk]);
#pragma unroll
          for (int cs = 0; cs < 2; ++cs) {
            short8 bf =
                *(const short8*)(&Vs[n][(ch << 5) + (cs << 4) + lrow][lk]);
            acc[cs] = mfma16x16x32(af, bf, acc[cs]);
          }
        }
        __syncthreads();
      }
      // ---- odd chunk: consume B; re-issue B <- ck+3 ----
      {
        u16 m4[4] = {(u16)puB.x, (u16)(puB.x >> 16), (u16)puB.y,
                     (u16)(puB.y >> 16)};
        u16 p[4];
#pragma unroll
        for (int j = 0; j < 4; ++j)
          p[j] = f2bf(__expf(bf2f(m4[j]) - rm) * rz);
        u8 mk[4] = {(u8)mkB, (u8)(mkB >> 8), (u8)(mkB >> 16), (u8)(mkB >> 24)};
#pragma unroll
        for (int n = 0; n < NB_; ++n) {
          uint2 wv;
          wv.x = (unsigned)(((mk[0] >> n) & 1) ? p[0] : 0) |
                 ((unsigned)(((mk[1] >> n) & 1) ? p[1] : 0) << 16);
          wv.y = (unsigned)(((mk[2] >> n) & 1) ? p[2] : 0) |
                 ((unsigned)(((mk[3] >> n) & 1) ? p[3] : 0) << 16);
          *(uint2*)(&Ps[n][row8][scol]) = wv;
          *(uint2*)(&Vs[n][row8][scol]) = vvB[n];
        }
        if (ck + 3 < nchunk) {  // B regs free -> issue ck+3
          const int sB = (ck + 3) << 5;
          puB = *(const uint2*)(&Mb[pro + sB + off4]);
          mkB = *(const unsigned*)(&Mask[pro + sB + off4]);
#pragma unroll
          for (int n = 0; n < NB_; ++n)
            vvB[n] = *(const uint2*)(&VT[vrow_base[n] + sB + off4]);
        }
        __syncthreads();
#pragma unroll
        for (int n = 0; n < NB_; ++n) {
          short8 af = *(const short8*)(&Ps[n][(wq << 4) + lrow][lk]);
#pragma unroll
          for (int cs = 0; cs < 2; ++cs) {
            short8 bf =
                *(const short8*)(&Vs[n][(ch << 5) + (cs << 4) + lrow][lk]);
            acc[cs] = mfma16x16x32(af, bf, acc[cs]);
          }
        }
        __syncthreads();
      }
    }
    const int tb = t0 + (wq << 4) + ((lane >> 4) << 2);
    const int cbs = c0 + (ch << 5) + (lane & 15);
#pragma unroll
    for (int cs = 0; cs < 2; ++cs) {
#pragma unroll
      for (int r = 0; r < 4; ++r) {
        Y[(size_t)((b << 11) + tb + r) * C_ + cbs + (cs << 4)] =
            f2bf(acc[cs][r]);
      }
    }
  }
}

// ---------------------------------------------------------------------------
extern "C" void kernel_launch(void* const* d_in, const int* in_sizes, int n_in,
                              void* d_out, int out_size, void* d_ws,
                              size_t ws_size, hipStream_t stream) {
  (void)in_sizes; (void)n_in; (void)out_size; (void)ws_size;
  const float* a    = (const float*)d_in[0];
  const float* x    = (const float*)d_in[1];
  const float* Wq   = (const float*)d_in[2];
  const float* Wk   = (const float*)d_in[3];
  const float* Wv   = (const float*)d_in[4];
  const float* Wo   = (const float*)d_in[5];
  const float* cosT = (const float*)d_in[6];
  const float* sinT = (const float*)d_in[7];

  char* w = (char*)d_ws;
  u16* Qcat   = (u16*)(w + 0);           // 33.5MB -> first 4.2MB reused as Y
  u16* Kcat   = (u16*)(w + 33554432);    //  8.4MB
  u16* Vraw   = (u16*)(w + 41943040);    // 16.8MB -> reused as bf16 M
  u16* VT     = (u16*)(w + 58720256);    // 16.8MB
  u8*  Mask   = (u8*)(w + 75497472);     //  8.4MB
  float* Rm   = (float*)(w + 83886080);  //  16KB
  float* Rz   = (float*)(w + 83902464);  //  16KB
  u16* Acat   = (u16*)(w + 83918848);    //  8.4MB (freed Pb slot)
  u16* WTq    = (u16*)(w + 92307456);    //  4.2MB
  u16* WTv    = (u16*)(w + 96501760);    //  2.0MB (end 98,598,912)
  u16* Mb     = Vraw;
  u16* Y      = Qcat;

  const dim3 blk(256);
  split_a_k<<<dim3(1024), blk, 0, stream>>>(a, Acat);
  splitT_w_k<1><<<dim3(32, 8), blk, 0, stream>>>(Wq, WTq, 2048);
  splitT_w_k<0><<<dim3(32, 8), blk, 0, stream>>>(Wv, WTv, 2048);
  gemm_qk_pre<<<dim3(32, 64), blk, 0, stream>>>(Acat, WTq, Qcat, cosT, sinT);
  gemm_qk<2><<<dim3(8, 64), blk, 0, stream>>>(x, Wk, Kcat, cosT, sinT, 512, 512);
  gemm_bb<<<dim3(32, 64), blk, 0, stream>>>(Acat, WTv, Vraw);
  transpose_v_k<<<dim3(2048), blk, 0, stream>>>(Vraw, VT);
  scores_k<<<dim3(272, 2), blk, 0, stream>>>(Qcat, Kcat, Mb, Mask);
  rowstats_k<<<dim3(1024), blk, 0, stream>>>(Mb, Rm, Rz);
  pv_k<<<dim3(8, 16, 2), dim3(512), 0, stream>>>(Mb, Rm, Rz, Mask, VT, Y);
  gemm_hi<0, 1><<<dim3(8, 64), blk, 0, stream>>>(Y, Wo, d_out, 512, 512);
}

// Round 16
// 316.329 us; speedup vs baseline: 1.0878x; 1.0878x over previous
//
#include <hip/hip_runtime.h>
#include <math.h>

// ============================================================================
// R28: consolidation -- exact revert of scores_k to the R24/R26 proven form.
// R27's Q-reuse pairing (48KB LDS, 140 VGPR, 32x f32x4 acc) collapsed
// occupancy 21.5->8.0% and regressed scores 71.6->92.8us (total 344.1).
// Session law (6 data points: R15/R16/R17/R21/R22/R27): in these
// barrier-locked staging loops, >=2 blocks/CU beats every staging-work
// optimization that costs occupancy. Restore the verified session-best
// pipeline (R26, 317.6us): pre-split conversions + gload_lds GEMMs +
// R24 scores + R25 depth-2-prefetch pv + XCD pinning everywhere.
// Predicted: scores ~71-72us / Occ ~21.5 / VGPR 84; total ~317-320us.
// ============================================================================

#define B_ 2
#define T_ 2048
#define C_ 512
#define NB_ 4
#define C2_ 1024  // hi|lo row width

typedef unsigned short u16;
typedef unsigned char u8;
using short8 = __attribute__((ext_vector_type(8))) short;
using bf16x8 = __attribute__((ext_vector_type(8))) __bf16;
using f32x4  = __attribute__((ext_vector_type(4))) float;

__device__ __forceinline__ float bf2f(u16 u) {
  union { unsigned int i; float f; } v; v.i = ((unsigned int)u) << 16; return v.f;
}
__device__ __forceinline__ u16 f2bf(float f) {  // round-to-nearest-even
  union { float f; unsigned int i; } v; v.f = f;
  unsigned int u = v.i;
  return (u16)((u + 0x7fffu + ((u >> 16) & 1u)) >> 16);
}
__device__ __forceinline__ f32x4 mfma16x16x32(short8 a, short8 b, f32x4 c) {
  return __builtin_amdgcn_mfma_f32_16x16x32_bf16(
      __builtin_bit_cast(bf16x8, a), __builtin_bit_cast(bf16x8, b), c, 0, 0, 0);
}
__device__ __forceinline__ void split8(const float* s, uint4& hi, uint4& lo) {
  u16 h[8], l[8];
#pragma unroll
  for (int j = 0; j < 8; ++j) {
    h[j] = f2bf(s[j]);
    l[j] = f2bf(s[j] - bf2f(h[j]));
  }
  hi.x = h[0] | ((unsigned)h[1] << 16); hi.y = h[2] | ((unsigned)h[3] << 16);
  hi.z = h[4] | ((unsigned)h[5] << 16); hi.w = h[6] | ((unsigned)h[7] << 16);
  lo.x = l[0] | ((unsigned)l[1] << 16); lo.y = l[2] | ((unsigned)l[3] << 16);
  lo.z = l[4] | ((unsigned)l[5] << 16); lo.w = l[6] | ((unsigned)l[7] << 16);
}
// LDS bank swizzle: XOR the 16B column-group with row bits [2:1].
__device__ __forceinline__ int swz(int row) { return ((row >> 1) & 3) << 3; }

// ---------------------------------------------------------------------------
// Pre-pass 1: a (4096x512 f32) -> Acat (4096 x [hi512|lo512] u16).
// ---------------------------------------------------------------------------
__global__ __launch_bounds__(256) void split_a_k(const float* __restrict__ A,
                                                 u16* __restrict__ Acat) {
  const size_t base = ((size_t)blockIdx.x * 256 + threadIdx.x) << 3;
  const size_t row = base >> 9, col = base & 511;
  float av[8];
  *(float4*)(av) = *(const float4*)(&A[base]);
  *(float4*)(av + 4) = *(const float4*)(&A[base + 4]);
  uint4 hi, lo;
  split8(av, hi, lo);
  *(uint4*)(&Acat[row * C2_ + col]) = hi;
  *(uint4*)(&Acat[row * C2_ + C_ + col]) = lo;
}

// ---------------------------------------------------------------------------
// Pre-pass 2: W (512 x N f32) -> WT (N x [hi|lo] or hi-only), transposed.
// ---------------------------------------------------------------------------
template <int HILO>
__global__ __launch_bounds__(256) void splitT_w_k(const float* __restrict__ W,
                                                  u16* __restrict__ WT,
                                                  const int N) {
  __shared__ float tile[64][68];
  const int n0 = blockIdx.x << 6, k0 = blockIdx.y << 6;
  const int tid = threadIdx.x;
  const int rr = tid >> 4, cc = (tid & 15) << 2;
#pragma unroll
  for (int it = 0; it < 4; ++it) {
    const int kr = (it << 4) + rr;
    *(float4*)(&tile[kr][cc]) =
        *(const float4*)(&W[(size_t)(k0 + kr) * N + n0 + cc]);
  }
  __syncthreads();
  const int W2 = HILO ? C2_ : C_;
#pragma unroll
  for (int it = 0; it < 4; ++it) {
    const int nr = (it << 4) + rr;
    const int kc = cc;
    float v[4] = {tile[kc][nr], tile[kc + 1][nr], tile[kc + 2][nr],
                  tile[kc + 3][nr]};
    ushort4 hw, lw;
    hw.x = f2bf(v[0]); hw.y = f2bf(v[1]); hw.z = f2bf(v[2]); hw.w = f2bf(v[3]);
    *(ushort4*)(&WT[(size_t)(n0 + nr) * W2 + k0 + kc]) = hw;
    if (HILO) {
      lw.x = f2bf(v[0] - bf2f(hw.x)); lw.y = f2bf(v[1] - bf2f(hw.y));
      lw.z = f2bf(v[2] - bf2f(hw.z)); lw.w = f2bf(v[3] - bf2f(hw.w));
      *(ushort4*)(&WT[(size_t)(n0 + nr) * W2 + C_ + k0 + kc]) = lw;
    }
  }
}

// ---------------------------------------------------------------------------
// Q GEMM from pre-split inputs: Acat @ WTq -> Qcat with fused RoPE + scale.
// ---------------------------------------------------------------------------
__global__ __launch_bounds__(256) void gemm_qk_pre(const u16* __restrict__ Acat,
                                                   const u16* __restrict__ WT,
                                                   u16* __restrict__ out,
                                                   const float* __restrict__ cosT,
                                                   const float* __restrict__ sinT) {
  __shared__ __align__(16) u16 Ah[64][32], Al[64][32];
  __shared__ __align__(16) u16 Bh[64][32], Bl[64][32];
  const int tid = threadIdx.x;
  const int wave = tid >> 6, lane = tid & 63;
  const int m0 = blockIdx.y << 6, n0 = blockIdx.x << 6;
  const f32x4 zero = {0.f, 0.f, 0.f, 0.f};
  f32x4 acc[4] = {zero, zero, zero, zero};
  const int srow = tid >> 2, kg = (tid & 3) << 3;
  const int lrow = lane & 15, lk = (lane >> 4) << 3;
  const int wrow = wave << 4;
  const size_t abase = (size_t)(m0 + srow) * C2_ + kg;
  const size_t bbase = (size_t)(n0 + srow) * C2_ + kg;
  for (int kk = 0; kk < C_; kk += 32) {
    __builtin_amdgcn_global_load_lds(
        (const __attribute__((address_space(1))) void*)&Acat[abase + kk],
        (__attribute__((address_space(3))) void*)&Ah[wrow][0], 16, 0, 0);
    __builtin_amdgcn_global_load_lds(
        (const __attribute__((address_space(1))) void*)&Acat[abase + C_ + kk],
        (__attribute__((address_space(3))) void*)&Al[wrow][0], 16, 0, 0);
    __builtin_amdgcn_global_load_lds(
        (const __attribute__((address_space(1))) void*)&WT[bbase + kk],
        (__attribute__((address_space(3))) void*)&Bh[wrow][0], 16, 0, 0);
    __builtin_amdgcn_global_load_lds(
        (const __attribute__((address_space(1))) void*)&WT[bbase + C_ + kk],
        (__attribute__((address_space(3))) void*)&Bl[wrow][0], 16, 0, 0);
    __syncthreads();
    short8 ah = *(const short8*)(&Ah[(wave << 4) + lrow][lk]);
    short8 al = *(const short8*)(&Al[(wave << 4) + lrow][lk]);
#pragma unroll
    for (int ns = 0; ns < 4; ++ns) {
      short8 bh = *(const short8*)(&Bh[(ns << 4) + lrow][lk]);
      short8 bl = *(const short8*)(&Bl[(ns << 4) + lrow][lk]);
      acc[ns] = mfma16x16x32(ah, bh, acc[ns]);
      acc[ns] = mfma16x16x32(al, bh, acc[ns]);
      acc[ns] = mfma16x16x32(ah, bl, acc[ns]);
    }
    __syncthreads();
  }
  const int r0 = m0 + (wave << 4) + ((lane >> 4) << 2);
  const int cb = n0 + (lane & 15);
#pragma unroll
  for (int ns = 0; ns < 4; ++ns) {
#pragma unroll
    for (int r = 0; r < 4; ++r) {
      const int rg = r0 + r;
      const int cg = cb + (ns << 4);
      float v = acc[ns][r];
      float pv = __shfl_xor(v, 1);  // partner column of the RoPE pair
      const int t = rg & (T_ - 1);
      const int c = cg & (C_ - 1);
      const int i = c >> 1;
      const float cf = cosT[(t << 8) + i];
      const float sf = sinT[(t << 8) + i];
      float x1 = (lane & 1) ? pv : v;
      float x2 = (lane & 1) ? v : pv;
      float y = (lane & 1) ? (x1 * sf + x2 * cf) : (x1 * cf - x2 * sf);
      y *= 0.044194173824159216f;  // 1/sqrt(512)
      const u16 hi = f2bf(y);
      const u16 lo = f2bf(y - bf2f(hi));
      const int b = rg >> 11, n = cg >> 9;
      const size_t rowoff = ((size_t)((b * NB_ + n) * T_ + t)) * C2_;
      out[rowoff + c] = hi;
      out[rowoff + C_ + c] = lo;
    }
  }
}

// ---------------------------------------------------------------------------
// a@Wv from pre-split inputs: Acat hi-half @ WTv -> Vraw bf16 (4096x2048).
// ---------------------------------------------------------------------------
__global__ __launch_bounds__(256) void gemm_bb(const u16* __restrict__ Acat,
                                               const u16* __restrict__ WT,
                                               u16* __restrict__ out) {
  __shared__ __align__(16) u16 As[64][32];
  __shared__ __align__(16) u16 Bs[64][32];
  const int tid = threadIdx.x;
  const int wave = tid >> 6, lane = tid & 63;
  const int m0 = blockIdx.y << 6, n0 = blockIdx.x << 6;
  const f32x4 zero = {0.f, 0.f, 0.f, 0.f};
  f32x4 acc[4] = {zero, zero, zero, zero};
  const int srow = tid >> 2, kg = (tid & 3) << 3;
  const int lrow = lane & 15, lk = (lane >> 4) << 3;
  const int wrow = wave << 4;
  const size_t abase = (size_t)(m0 + srow) * C2_ + kg;  // hi half of Acat
  const size_t bbase = (size_t)(n0 + srow) * C_ + kg;   // WTv row width 512
  for (int kk = 0; kk < C_; kk += 32) {
    __builtin_amdgcn_global_load_lds(
        (const __attribute__((address_space(1))) void*)&Acat[abase + kk],
        (__attribute__((address_space(3))) void*)&As[wrow][0], 16, 0, 0);
    __builtin_amdgcn_global_load_lds(
        (const __attribute__((address_space(1))) void*)&WT[bbase + kk],
        (__attribute__((address_space(3))) void*)&Bs[wrow][0], 16, 0, 0);
    __syncthreads();
    short8 af = *(const short8*)(&As[(wave << 4) + lrow][lk]);
#pragma unroll
    for (int ns = 0; ns < 4; ++ns) {
      short8 bf = *(const short8*)(&Bs[(ns << 4) + lrow][lk]);
      acc[ns] = mfma16x16x32(af, bf, acc[ns]);
    }
    __syncthreads();
  }
  const int r0 = m0 + (wave << 4) + ((lane >> 4) << 2);
  const int cb = n0 + (lane & 15);
#pragma unroll
  for (int ns = 0; ns < 4; ++ns) {
#pragma unroll
    for (int r = 0; r < 4; ++r) {
      out[(size_t)(r0 + r) * (NB_ * C_) + cb + (ns << 4)] = f2bf(acc[ns][r]);
    }
  }
}

// ---------------------------------------------------------------------------
// Split-precision GEMM with fused RoPE (kept for x @ Wk -> Kcat only).
// ---------------------------------------------------------------------------
template <int MODE>
__global__ __launch_bounds__(256) void gemm_qk(const float* __restrict__ A,
                                               const float* __restrict__ W,
                                               u16* __restrict__ out,
                                               const float* __restrict__ cosT,
                                               const float* __restrict__ sinT,
                                               const int N, const int K) {
  __shared__ u16 Ah[64][32], Al[64][32];
  __shared__ u16 Bh[64][32], Bl[64][32];  // [n][k]
  const int tid = threadIdx.x;
  const int wave = tid >> 6, lane = tid & 63;
  const int m0 = blockIdx.y << 6, n0 = blockIdx.x << 6;
  const f32x4 zero = {0.f, 0.f, 0.f, 0.f};
  f32x4 acc[4] = {zero, zero, zero, zero};
  const int srow = tid >> 2, koff = ((tid & 3) << 3) ^ swz(tid >> 2);
  const int lrow = lane & 15, lk = ((lane >> 4) << 3) ^ swz(lane & 15);
  for (int kk = 0; kk < K; kk += 32) {
    const int kg = (tid & 3) << 3;  // global k sub-offset (unswizzled)
    float av[8];
    *(float4*)(av) = *(const float4*)(&A[(size_t)(m0 + srow) * K + kk + kg]);
    *(float4*)(av + 4) =
        *(const float4*)(&A[(size_t)(m0 + srow) * K + kk + kg + 4]);
    uint4 hi, lo;
    split8(av, hi, lo);
    *(uint4*)(&Ah[srow][koff]) = hi;
    *(uint4*)(&Al[srow][koff]) = lo;
    float wv[8];
#pragma unroll
    for (int j = 0; j < 8; ++j)
      wv[j] = W[(size_t)(kk + kg + j) * N + n0 + srow];
    split8(wv, hi, lo);
    *(uint4*)(&Bh[srow][koff]) = hi;
    *(uint4*)(&Bl[srow][koff]) = lo;
    __syncthreads();
    short8 ah = *(const short8*)(&Ah[(wave << 4) + lrow][lk]);
    short8 al = *(const short8*)(&Al[(wave << 4) + lrow][lk]);
#pragma unroll
    for (int ns = 0; ns < 4; ++ns) {
      short8 bh = *(const short8*)(&Bh[(ns << 4) + lrow][lk]);
      short8 bl = *(const short8*)(&Bl[(ns << 4) + lrow][lk]);
      acc[ns] = mfma16x16x32(ah, bh, acc[ns]);
      acc[ns] = mfma16x16x32(al, bh, acc[ns]);
      acc[ns] = mfma16x16x32(ah, bl, acc[ns]);
    }
    __syncthreads();
  }
  const int r0 = m0 + (wave << 4) + ((lane >> 4) << 2);
  const int cb = n0 + (lane & 15);
#pragma unroll
  for (int ns = 0; ns < 4; ++ns) {
#pragma unroll
    for (int r = 0; r < 4; ++r) {
      const int rg = r0 + r;
      const int cg = cb + (ns << 4);
      float v = acc[ns][r];
      float pv = __shfl_xor(v, 1);  // partner column of the RoPE pair
      const int t = rg & (T_ - 1);
      const int c = (MODE == 1) ? (cg & (C_ - 1)) : cg;
      const int i = c >> 1;
      const float cf = cosT[(t << 8) + i];
      const float sf = sinT[(t << 8) + i];
      float x1 = (lane & 1) ? pv : v;
      float x2 = (lane & 1) ? v : pv;
      float y = (lane & 1) ? (x1 * sf + x2 * cf) : (x1 * cf - x2 * sf);
      if (MODE == 1) y *= 0.044194173824159216f;  // 1/sqrt(512)
      const u16 hi = f2bf(y);
      const u16 lo = f2bf(y - bf2f(hi));
      size_t rowoff;
      if (MODE == 1) {
        const int b = rg >> 11, n = cg >> 9;
        rowoff = ((size_t)((b * NB_ + n) * T_ + t)) * C2_;
      } else {
        rowoff = (size_t)rg * C2_;
      }
      out[rowoff + c] = hi;
      out[rowoff + C_ + c] = lo;
    }
  }
}

// ---------------------------------------------------------------------------
// Plain hi-only GEMM (kept for Y @ Wo): A bf16, W f32; out f32.
// ---------------------------------------------------------------------------
template <int AF32, int OF32>
__global__ __launch_bounds__(256) void gemm_hi(const void* __restrict__ Ap,
                                               const float* __restrict__ W,
                                               void* __restrict__ outp,
                                               const int N, const int K) {
  __shared__ u16 As[64][32];
  __shared__ u16 Bs[64][32];
  const int tid = threadIdx.x;
  const int wave = tid >> 6, lane = tid & 63;
  const int m0 = blockIdx.y << 6, n0 = blockIdx.x << 6;
  const f32x4 zero = {0.f, 0.f, 0.f, 0.f};
  f32x4 acc[4] = {zero, zero, zero, zero};
  const int srow = tid >> 2, koff = ((tid & 3) << 3) ^ swz(tid >> 2);
  const int lrow = lane & 15, lk = ((lane >> 4) << 3) ^ swz(lane & 15);
  for (int kk = 0; kk < K; kk += 32) {
    const int kg = (tid & 3) << 3;
    if (AF32) {
      const float* A = (const float*)Ap;
      float av[8];
      *(float4*)(av) = *(const float4*)(&A[(size_t)(m0 + srow) * K + kk + kg]);
      *(float4*)(av + 4) =
          *(const float4*)(&A[(size_t)(m0 + srow) * K + kk + kg + 4]);
      uint4 hi;
      hi.x = f2bf(av[0]) | ((unsigned)f2bf(av[1]) << 16);
      hi.y = f2bf(av[2]) | ((unsigned)f2bf(av[3]) << 16);
      hi.z = f2bf(av[4]) | ((unsigned)f2bf(av[5]) << 16);
      hi.w = f2bf(av[6]) | ((unsigned)f2bf(av[7]) << 16);
      *(uint4*)(&As[srow][koff]) = hi;
    } else {
      const u16* A = (const u16*)Ap;
      *(uint4*)(&As[srow][koff]) =
          *(const uint4*)(&A[(size_t)(m0 + srow) * K + kk + kg]);
    }
    uint4 hi;
    {
      float w[8];
#pragma unroll
      for (int j = 0; j < 8; ++j)
        w[j] = W[(size_t)(kk + kg + j) * N + n0 + srow];
      hi.x = f2bf(w[0]) | ((unsigned)f2bf(w[1]) << 16);
      hi.y = f2bf(w[2]) | ((unsigned)f2bf(w[3]) << 16);
      hi.z = f2bf(w[4]) | ((unsigned)f2bf(w[5]) << 16);
      hi.w = f2bf(w[6]) | ((unsigned)f2bf(w[7]) << 16);
    }
    *(uint4*)(&Bs[srow][koff]) = hi;
    __syncthreads();
    short8 af = *(const short8*)(&As[(wave << 4) + lrow][lk]);
#pragma unroll
    for (int ns = 0; ns < 4; ++ns) {
      short8 bf = *(const short8*)(&Bs[(ns << 4) + lrow][lk]);
      acc[ns] = mfma16x16x32(af, bf, acc[ns]);
    }
    __syncthreads();
  }
  const int r0 = m0 + (wave << 4) + ((lane >> 4) << 2);
  const int cb = n0 + (lane & 15);
#pragma unroll
  for (int ns = 0; ns < 4; ++ns) {
#pragma unroll
    for (int r = 0; r < 4; ++r) {
      const size_t idx = (size_t)(r0 + r) * N + cb + (ns << 4);
      if (OF32) ((float*)outp)[idx] = acc[ns][r];
      else ((u16*)outp)[idx] = f2bf(acc[ns][r]);
    }
  }
}

// ---------------------------------------------------------------------------
// Vraw (B,T,NB*C) bf16 -> VT (B,NB,C,T) tiled transpose, 64x64 tiles.
// ---------------------------------------------------------------------------
__global__ __launch_bounds__(256) void transpose_v_k(const u16* __restrict__ Vraw,
                                                     u16* __restrict__ VT) {
  const int bid = blockIdx.x;
  const int ct = bid & 7;
  const int ttile = (bid >> 3) & 31;
  const int n = (bid >> 8) & 3;
  const int b = bid >> 10;
  __shared__ u16 tile[64][68];
  const int tid = threadIdx.x;
  const int rr = tid >> 4;
  const int cc = (tid & 15) << 2;
  const int t0 = ttile << 6, c0 = ct << 6;
#pragma unroll
  for (int it = 0; it < 4; ++it) {
    const int r = (it << 4) + rr;
    *(ushort4*)(&tile[r][cc]) = *(const ushort4*)(
        &Vraw[((size_t)((b << 11) + t0 + r)) * (NB_ * C_) + n * C_ + c0 + cc]);
  }
  __syncthreads();
#pragma unroll
  for (int it = 0; it < 4; ++it) {
    const int c = (it << 4) + rr;
    ushort4 w;
    w.x = tile[cc + 0][c]; w.y = tile[cc + 1][c];
    w.z = tile[cc + 2][c]; w.w = tile[cc + 3][c];
    *(ushort4*)(&VT[((size_t)((b * NB_ + n) * C_ + c0 + c)) * T_ + t0 + cc]) = w;
  }
}

// ---------------------------------------------------------------------------
// Scores (R24/R26 proven form): single-buffered 40KB LDS, __syncthreads
// lockstep, XCD-chunked tri swizzle, staging via global_load_lds width=16
// (linear LDS). 84 VGPR, ~21.5% occupancy.
// ---------------------------------------------------------------------------
__global__ __launch_bounds__(256) void scores_k(const u16* __restrict__ Qcat,
                                                const u16* __restrict__ Kcat,
                                                u16* __restrict__ Mout,
                                                u8* __restrict__ Mask) {
  // XCD-chunked swizzle: 8 XCDs x 66 consecutive tris each (bijective).
  const int tri = ((blockIdx.x & 7) * 66) + (blockIdx.x >> 3);
  int tt = (int)((sqrtf(8.f * (float)tri + 1.f) - 1.f) * 0.5f);
  while ((tt + 1) * (tt + 2) / 2 <= tri) ++tt;
  while (tt * (tt + 1) / 2 > tri) --tt;
  const int ss = tri - tt * (tt + 1) / 2;
  const int b = blockIdx.y;
  __shared__ __align__(16) u16 Qh[NB_][64][32], Ql[NB_][64][32];
  __shared__ __align__(16) u16 Kh[64][32], Kl[64][32];
  const int tid = threadIdx.x;
  const int wave = tid >> 6, lane = tid & 63;
  const int t0 = tt << 6, s0 = ss << 6;
  const f32x4 zero = {0.f, 0.f, 0.f, 0.f};
  f32x4 acc[NB_][4];
  for (int n = 0; n < NB_; ++n)
    for (int j = 0; j < 4; ++j) acc[n][j] = zero;
  const int srow = tid >> 2, kg = (tid & 3) << 3;
  const int lrow = lane & 15, lk = (lane >> 4) << 3;
  const int wrow = wave << 4;
  const size_t qstride = (size_t)T_ * C2_;
  const size_t qbase = ((size_t)(b * NB_ * T_ + t0 + srow)) * C2_ + kg;
  const size_t kbase = ((size_t)((b << 11) + s0 + srow)) * C2_ + kg;

  for (int kk = 0; kk < C_; kk += 32) {
#pragma unroll
    for (int n = 0; n < NB_; ++n) {
      const size_t qb = qbase + (size_t)n * qstride + kk;
      __builtin_amdgcn_global_load_lds(
          (const __attribute__((address_space(1))) void*)&Qcat[qb],
          (__attribute__((address_space(3))) void*)&Qh[n][wrow][0], 16, 0, 0);
      __builtin_amdgcn_global_load_lds(
          (const __attribute__((address_space(1))) void*)&Qcat[qb + C_],
          (__attribute__((address_space(3))) void*)&Ql[n][wrow][0], 16, 0, 0);
    }
    __builtin_amdgcn_global_load_lds(
        (const __attribute__((address_space(1))) void*)&Kcat[kbase + kk],
        (__attribute__((address_space(3))) void*)&Kh[wrow][0], 16, 0, 0);
    __builtin_amdgcn_global_load_lds(
        (const __attribute__((address_space(1))) void*)&Kcat[kbase + kk + C_],
        (__attribute__((address_space(3))) void*)&Kl[wrow][0], 16, 0, 0);
    __syncthreads();  // drains vmcnt(0): staged data visible block-wide
    short8 qh[NB_], ql[NB_];
#pragma unroll
    for (int n = 0; n < NB_; ++n) {
      qh[n] = *(const short8*)(&Qh[n][wrow + lrow][lk]);
      ql[n] = *(const short8*)(&Ql[n][wrow + lrow][lk]);
    }
#pragma unroll
    for (int ns = 0; ns < 4; ++ns) {
      short8 kh = *(const short8*)(&Kh[(ns << 4) + lrow][lk]);
      short8 kl = *(const short8*)(&Kl[(ns << 4) + lrow][lk]);
#pragma unroll
      for (int n = 0; n < NB_; ++n) {
        acc[n][ns] = mfma16x16x32(qh[n], kh, acc[n][ns]);
        acc[n][ns] = mfma16x16x32(ql[n], kh, acc[n][ns]);
        acc[n][ns] = mfma16x16x32(qh[n], kl, acc[n][ns]);
      }
    }
    __syncthreads();  // all reads done before next-iter re-stage
  }
  const int tb = t0 + (wave << 4) + ((lane >> 4) << 2);
  const int sb = s0 + (lane & 15);
#pragma unroll
  for (int ns = 0; ns < 4; ++ns) {
#pragma unroll
    for (int r = 0; r < 4; ++r) {
      const int t = tb + r, s = sb + (ns << 4);
      float a0 = acc[0][ns][r], a1 = acc[1][ns][r];
      float a2 = acc[2][ns][r], a3 = acc[3][ns][r];
      float m = fmaxf(fmaxf(a0, a1), fmaxf(a2, a3));
      u8 msk = (u8)((a0 == m) | ((a1 == m) << 1) | ((a2 == m) << 2) |
                    ((a3 == m) << 3));
      if (s > t) { m = -__builtin_inff(); msk = 0; }
      const size_t idx = (size_t)b * T_ * T_ + (size_t)t * T_ + s;
      Mout[idx] = f2bf(m);
      Mask[idx] = msk;
    }
  }
}

// ---------------------------------------------------------------------------
// Per-row softmax stats from bf16 M: rowmax, 1/sum(exp). One wave per (b,t).
// ---------------------------------------------------------------------------
__global__ __launch_bounds__(256) void rowstats_k(const u16* __restrict__ Mb,
                                                  float* __restrict__ Rm,
                                                  float* __restrict__ Rz) {
  const int r = (blockIdx.x << 2) + (threadIdx.x >> 6);
  const int lane = threadIdx.x & 63;
  const int b = r >> 11, t = r & (T_ - 1);
  const u16* row = Mb + (size_t)b * T_ * T_ + (size_t)t * T_;
  float m = -__builtin_inff();
  for (int s = lane; s <= t; s += 64) m = fmaxf(m, bf2f(row[s]));
#pragma unroll
  for (int off = 32; off; off >>= 1) m = fmaxf(m, __shfl_xor(m, off));
  float z = 0.f;
  for (int s = lane; s <= t; s += 64) z += __expf(bf2f(row[s]) - m);
#pragma unroll
  for (int off = 32; off; off >>= 1) z += __shfl_xor(z, off);
  if (lane == 0) { Rm[r] = m; Rz[r] = 1.f / z; }
}

// ---------------------------------------------------------------------------
// Routed PV (R25 form): depth-2 named A/B register prefetch, 512-thread
// blocks, 64-wide c stripe, grid (8,16,2) XCD V-panel pinning, fused
// P-build + __expf, LDS 32KB, col^swz(row) LDS swizzle.
// ---------------------------------------------------------------------------
__global__ __launch_bounds__(512) void pv_k(const u16* __restrict__ Mb,
                                            const float* __restrict__ Rm,
                                            const float* __restrict__ Rz,
                                            const u8* __restrict__ Mask,
                                            const u16* __restrict__ VT,
                                            u16* __restrict__ Y) {
  const int cblk = blockIdx.x, ypair = blockIdx.y, b = blockIdx.z;
  const int c0 = cblk << 6;  // 64-wide c stripe
  __shared__ u16 Ps[NB_][64][32];
  __shared__ u16 Vs[NB_][64][32];
  const int tid = threadIdx.x;
  const int wave = tid >> 6, lane = tid & 63;
  const int wq = wave & 3, ch = wave >> 2;            // t-quarter, c-half
  const int row8 = tid >> 3, off4 = (tid & 7) << 2;   // 64 rows x uint2
  const int scol = off4 ^ swz(row8);                  // swizzled LDS col
  const int lrow = lane & 15, lk = ((lane >> 4) << 3) ^ swz(lane & 15);
  const f32x4 zero = {0.f, 0.f, 0.f, 0.f};
  const size_t vrow_base[NB_] = {
      ((size_t)((b * NB_ + 0) * C_ + c0 + row8)) * T_,
      ((size_t)((b * NB_ + 1) * C_ + c0 + row8)) * T_,
      ((size_t)((b * NB_ + 2) * C_ + c0 + row8)) * T_,
      ((size_t)((b * NB_ + 3) * C_ + c0 + row8)) * T_};

  for (int half = 0; half < 2; ++half) {
    const int tt = half ? (31 - ypair) : ypair;
    const int t0 = tt << 6;
    const int nchunk = (tt + 1) << 1;  // ALWAYS EVEN
    const int rg = (b << 11) + t0 + row8;       // this thread's (b,t) row
    const size_t pro = (size_t)rg << 11;
    const float rm = Rm[rg], rz = Rz[rg];       // per-row scalars, once/half
    f32x4 acc[2] = {zero, zero};
    // Named depth-2 prefetch sets (rule #20: no runtime-indexed reg arrays).
    uint2 puA, puB; unsigned mkA, mkB; uint2 vvA[NB_], vvB[NB_];

    // prologue: chunk 0 -> A, chunk 1 -> B
    puA = *(const uint2*)(&Mb[pro + off4]);
    mkA = *(const unsigned*)(&Mask[pro + off4]);
#pragma unroll
    for (int n = 0; n < NB_; ++n)
      vvA[n] = *(const uint2*)(&VT[vrow_base[n] + off4]);
    puB = *(const uint2*)(&Mb[pro + 32 + off4]);
    mkB = *(const unsigned*)(&Mask[pro + 32 + off4]);
#pragma unroll
    for (int n = 0; n < NB_; ++n)
      vvB[n] = *(const uint2*)(&VT[vrow_base[n] + 32 + off4]);

    for (int ck = 0; ck < nchunk; ck += 2) {
      // ---- even chunk: consume A; re-issue A <- ck+2 ----
      {
        u16 m4[4] = {(u16)puA.x, (u16)(puA.x >> 16), (u16)puA.y,
                     (u16)(puA.y >> 16)};
        u16 p[4];
#pragma unroll
        for (int j = 0; j < 4; ++j)
          p[j] = f2bf(__expf(bf2f(m4[j]) - rm) * rz);
        u8 mk[4] = {(u8)mkA, (u8)(mkA >> 8), (u8)(mkA >> 16), (u8)(mkA >> 24)};
#pragma unroll
        for (int n = 0; n < NB_; ++n) {
          uint2 wv;
          wv.x = (unsigned)(((mk[0] >> n) & 1) ? p[0] : 0) |
                 ((unsigned)(((mk[1] >> n) & 1) ? p[1] : 0) << 16);
          wv.y = (unsigned)(((mk[2] >> n) & 1) ? p[2] : 0) |
                 ((unsigned)(((mk[3] >> n) & 1) ? p[3] : 0) << 16);
          *(uint2*)(&Ps[n][row8][scol]) = wv;
          *(uint2*)(&Vs[n][row8][scol]) = vvA[n];
        }
        if (ck + 2 < nchunk) {  // A regs free -> issue ck+2 (2-chunk coverage)
          const int sB = (ck + 2) << 5;
          puA = *(const uint2*)(&Mb[pro + sB + off4]);
          mkA = *(const unsigned*)(&Mask[pro + sB + off4]);
#pragma unroll
          for (int n = 0; n < NB_; ++n)
            vvA[n] = *(const uint2*)(&VT[vrow_base[n] + sB + off4]);
        }
        __syncthreads();
#pragma unroll
        for (int n = 0; n < NB_; ++n) {
          short8 af = *(const short8*)(&Ps[n][(wq << 4) + lrow][lk]);
#pragma unroll
          for (int cs = 0; cs < 2; ++cs) {
            short8 bf =
                *(const short8*)(&Vs[n][(ch << 5) + (cs << 4) + lrow][lk]);
            acc[cs] = mfma16x16x32(af, bf, acc[cs]);
          }
        }
        __syncthreads();
      }
      // ---- odd chunk: consume B; re-issue B <- ck+3 ----
      {
        u16 m4[4] = {(u16)puB.x, (u16)(puB.x >> 16), (u16)puB.y,
                     (u16)(puB.y >> 16)};
        u16 p[4];
#pragma unroll
        for (int j = 0; j < 4; ++j)
          p[j] = f2bf(__expf(bf2f(m4[j]) - rm) * rz);
        u8 mk[4] = {(u8)mkB, (u8)(mkB >> 8), (u8)(mkB >> 16), (u8)(mkB >> 24)};
#pragma unroll
        for (int n = 0; n < NB_; ++n) {
          uint2 wv;
          wv.x = (unsigned)(((mk[0] >> n) & 1) ? p[0] : 0) |
                 ((unsigned)(((mk[1] >> n) & 1) ? p[1] : 0) << 16);
          wv.y = (unsigned)(((mk[2] >> n) & 1) ? p[2] : 0) |
                 ((unsigned)(((mk[3] >> n) & 1) ? p[3] : 0) << 16);
          *(uint2*)(&Ps[n][row8][scol]) = wv;
          *(uint2*)(&Vs[n][row8][scol]) = vvB[n];
        }
        if (ck + 3 < nchunk) {  // B regs free -> issue ck+3
          const int sB = (ck + 3) << 5;
          puB = *(const uint2*)(&Mb[pro + sB + off4]);
          mkB = *(const unsigned*)(&Mask[pro + sB + off4]);
#pragma unroll
          for (int n = 0; n < NB_; ++n)
            vvB[n] = *(const uint2*)(&VT[vrow_base[n] + sB + off4]);
        }
        __syncthreads();
#pragma unroll
        for (int n = 0; n < NB_; ++n) {
          short8 af = *(const short8*)(&Ps[n][(wq << 4) + lrow][lk]);
#pragma unroll
          for (int cs = 0; cs < 2; ++cs) {
            short8 bf =
                *(const short8*)(&Vs[n][(ch << 5) + (cs << 4) + lrow][lk]);
            acc[cs] = mfma16x16x32(af, bf, acc[cs]);
          }
        }
        __syncthreads();
      }
    }
    const int tb = t0 + (wq << 4) + ((lane >> 4) << 2);
    const int cbs = c0 + (ch << 5) + (lane & 15);
#pragma unroll
    for (int cs = 0; cs < 2; ++cs) {
#pragma unroll
      for (int r = 0; r < 4; ++r) {
        Y[(size_t)((b << 11) + tb + r) * C_ + cbs + (cs << 4)] =
            f2bf(acc[cs][r]);
      }
    }
  }
}

// ---------------------------------------------------------------------------
extern "C" void kernel_launch(void* const* d_in, const int* in_sizes, int n_in,
                              void* d_out, int out_size, void* d_ws,
                              size_t ws_size, hipStream_t stream) {
  (void)in_sizes; (void)n_in; (void)out_size; (void)ws_size;
  const float* a    = (const float*)d_in[0];
  const float* x    = (const float*)d_in[1];
  const float* Wq   = (const float*)d_in[2];
  const float* Wk   = (const float*)d_in[3];
  const float* Wv   = (const float*)d_in[4];
  const float* Wo   = (const float*)d_in[5];
  const float* cosT = (const float*)d_in[6];
  const float* sinT = (const float*)d_in[7];

  char* w = (char*)d_ws;
  u16* Qcat   = (u16*)(w + 0);           // 33.5MB -> first 4.2MB reused as Y
  u16* Kcat   = (u16*)(w + 33554432);    //  8.4MB
  u16* Vraw   = (u16*)(w + 41943040);    // 16.8MB -> reused as bf16 M
  u16* VT     = (u16*)(w + 58720256);    // 16.8MB
  u8*  Mask   = (u8*)(w + 75497472);     //  8.4MB
  float* Rm   = (float*)(w + 83886080);  //  16KB
  float* Rz   = (float*)(w + 83902464);  //  16KB
  u16* Acat   = (u16*)(w + 83918848);    //  8.4MB (freed Pb slot)
  u16* WTq    = (u16*)(w + 92307456);    //  4.2MB
  u16* WTv    = (u16*)(w + 96501760);    //  2.0MB (end 98,598,912)
  u16* Mb     = Vraw;
  u16* Y      = Qcat;

  const dim3 blk(256);
  split_a_k<<<dim3(1024), blk, 0, stream>>>(a, Acat);
  splitT_w_k<1><<<dim3(32, 8), blk, 0, stream>>>(Wq, WTq, 2048);
  splitT_w_k<0><<<dim3(32, 8), blk, 0, stream>>>(Wv, WTv, 2048);
  gemm_qk_pre<<<dim3(32, 64), blk, 0, stream>>>(Acat, WTq, Qcat, cosT, sinT);
  gemm_qk<2><<<dim3(8, 64), blk, 0, stream>>>(x, Wk, Kcat, cosT, sinT, 512, 512);
  gemm_bb<<<dim3(32, 64), blk, 0, stream>>>(Acat, WTv, Vraw);
  transpose_v_k<<<dim3(2048), blk, 0, stream>>>(Vraw, VT);
  scores_k<<<dim3(528, 2), blk, 0, stream>>>(Qcat, Kcat, Mb, Mask);
  rowstats_k<<<dim3(1024), blk, 0, stream>>>(Mb, Rm, Rz);
  pv_k<<<dim3(8, 16, 2), dim3(512), 0, stream>>>(Mb, Rm, Rz, Mask, VT, Y);
  gemm_hi<0, 1><<<dim3(8, 64), blk, 0, stream>>>(Y, Wo, d_out, 512, 512);
}